// Round 3
// baseline (546.051 us; speedup 1.0000x reference)
//
#include <hip/hip_runtime.h>
#include <hip/hip_bf16.h>
#include <cstdint>
#include <cstddef>

// MoE dims (fixed by the problem)
#define N_TOK 16384
#define DM    512
#define HD    2048
#define NE    8
#define TOPK  2

// GEMM tiling
#define BM 128
#define BN 128
#define BK 64
#define MAX_TILES 264   // sum ceil(count_e/128), sum count = 32768 -> <= 256+8

// Router tiling
#define RT_TOK 128
#define RT_DC  32

typedef __bf16  bf16x8 __attribute__((ext_vector_type(8)));
typedef float   f32x4  __attribute__((ext_vector_type(4)));

typedef const __attribute__((address_space(1))) void* gas_ptr;
typedef __attribute__((address_space(3))) void*       las_ptr;

__device__ __forceinline__ void async_copy16(const void* g, void* l) {
    __builtin_amdgcn_global_load_lds((gas_ptr)g, (las_ptr)l, 16, 0, 0);
}

// ---------------- init: zero out (N*D floats + 1 loss scalar) and counts ----
__global__ void k_init(float* __restrict__ out, int* __restrict__ count) {
    size_t i = (size_t)blockIdx.x * 256 + threadIdx.x;   // 8192*256 = N*D/4 exactly
    float4 z = make_float4(0.f, 0.f, 0.f, 0.f);
    ((float4*)out)[i] = z;
    if (i == 0) out[(size_t)N_TOK * DM] = 0.f;           // total_loss = 0
    if (i < NE) count[i] = 0;
}

// ---------------- per-expert transpose + convert: [E][R][C] f32 -> [E][C][R] bf16
__global__ void k_transpose(const float* __restrict__ in, __hip_bfloat16* __restrict__ outp,
                            int R, int C) {
    __shared__ float tile[32][33];
    const int e = blockIdx.z;
    const float* A = in + (size_t)e * R * C;
    __hip_bfloat16* B = outp + (size_t)e * R * C;
    const int c0 = blockIdx.x * 32, r0 = blockIdx.y * 32;
    const int tx = threadIdx.x & 31, ty = threadIdx.x >> 5;   // 32 x 8
#pragma unroll
    for (int i = 0; i < 32; i += 8)
        tile[ty + i][tx] = A[(size_t)(r0 + ty + i) * C + c0 + tx];
    __syncthreads();
#pragma unroll
    for (int i = 0; i < 32; i += 8)
        B[(size_t)(c0 + ty + i) * R + r0 + tx] = __float2bfloat16(tile[tx][ty + i]);
}

// ---------------- router: thread-per-token, LDS-staged X; fuses X->bf16 -----
__global__ __launch_bounds__(RT_TOK)
void k_router(const float* __restrict__ X, const float* __restrict__ Wr,
              int* __restrict__ count, int* __restrict__ list,
              float* __restrict__ gatev, uint2* __restrict__ Xb4) {
    __shared__ float sW[DM * NE];              // 16 KB, [d][e] row-major like Wr
    __shared__ float sX[RT_TOK][RT_DC + 1];    // +1 pad: lanes hit 2/bank (free)
    const int t = threadIdx.x;
    const int tok = blockIdx.x * RT_TOK + t;
    for (int i = t; i < DM * NE; i += RT_TOK) sW[i] = Wr[i];

    double acc[NE];
#pragma unroll
    for (int e = 0; e < NE; ++e) acc[e] = 0.0;

    const float4* X4 = (const float4*)X;
    for (int d0 = 0; d0 < DM; d0 += RT_DC) {
        __syncthreads();
        const int base4 = blockIdx.x * RT_TOK * (DM / 4) + d0 / 4;
#pragma unroll
        for (int j = 0; j < (RT_TOK * RT_DC / 4) / RT_TOK; ++j) {  // 8 float4/thread
            int i = t + RT_TOK * j;
            int r = i >> 3, c4 = i & 7;                   // RT_DC/4 = 8 vec4 per row
            float4 v = X4[base4 + r * (DM / 4) + c4];
            sX[r][c4 * 4 + 0] = v.x;
            sX[r][c4 * 4 + 1] = v.y;
            sX[r][c4 * 4 + 2] = v.z;
            sX[r][c4 * 4 + 3] = v.w;
            // fused fp32 -> bf16 convert (replaces the separate k_cvt_x pass)
            union { __hip_bfloat16 h[4]; uint2 u; } cv;
            cv.h[0] = __float2bfloat16(v.x);
            cv.h[1] = __float2bfloat16(v.y);
            cv.h[2] = __float2bfloat16(v.z);
            cv.h[3] = __float2bfloat16(v.w);
            Xb4[base4 + r * (DM / 4) + c4] = cv.u;
        }
        __syncthreads();
#pragma unroll
        for (int j = 0; j < RT_DC; ++j) {
            double xv = (double)sX[t][j];
            const float* w = &sW[(d0 + j) * NE];
#pragma unroll
            for (int e = 0; e < NE; ++e) acc[e] += xv * (double)w[e];
        }
    }

    // softmax + top-2 (ties -> lowest index, matching jax.lax.top_k)
    double mx = acc[0];
#pragma unroll
    for (int e = 1; e < NE; ++e) mx = acc[e] > mx ? acc[e] : mx;
    double p[NE], sum = 0.0;
#pragma unroll
    for (int e = 0; e < NE; ++e) { p[e] = exp(acc[e] - mx); sum += p[e]; }
    int i1 = 0;
#pragma unroll
    for (int e = 1; e < NE; ++e) if (acc[e] > acc[i1]) i1 = e;
    int i2 = (i1 == 0) ? 1 : 0;
#pragma unroll
    for (int e = 0; e < NE; ++e) {
        if (e == i1 || e == i2) continue;
        if (acc[e] > acc[i2]) i2 = e;
    }
    float v1 = (float)(p[i1] / sum), v2 = (float)(p[i2] / sum);

    // wave-aggregated append: <=16 atomics per wave instead of 128
    const int lane = t & 63;
#pragma unroll
    for (int k = 0; k < TOPK; ++k) {
        int   my_e = (k == 0) ? i1 : i2;
        float my_v = (k == 0) ? v1 : v2;
        for (int e = 0; e < NE; ++e) {
            unsigned long long msk = __ballot(my_e == e);
            if (!msk) continue;
            int leader = __ffsll(msk) - 1;
            int base = 0;
            if (lane == leader) base = atomicAdd(&count[e], __popcll(msk));
            base = __shfl(base, leader);
            if (my_e == e) {
                int pos = base + __popcll(msk & ((1ull << lane) - 1));
                list[e * N_TOK + pos]  = tok;
                gatev[e * N_TOK + pos] = my_v;
            }
        }
    }
}

// ---------------- schedule: per-expert tile list + h-row prefix bases -------
__global__ void k_sched(const int* __restrict__ count, int* __restrict__ hbase,
                        int* __restrict__ tileExpert, int* __restrict__ tileRow,
                        int* __restrict__ nTiles) {
    if (threadIdx.x == 0 && blockIdx.x == 0) {
        int hb = 0, tc = 0;
        for (int e = 0; e < NE; ++e) {
            hbase[e] = hb;
            int tiles = (count[e] + BM - 1) / BM;
            for (int i = 0; i < tiles; ++i) { tileExpert[tc] = e; tileRow[tc] = i; ++tc; }
            hb += count[e];
        }
        *nTiles = tc;
    }
}

// XCD-aware swizzle: the NCOL column-tiles of one row-tile get block ids that
// are congruent mod 8 -> same XCD -> the A row-slab is fetched once per XCD.
// L in [0, 8*NCOL*chunks): row = (L/(8*NCOL))*8 + L%8, col = (L>>3) % NCOL.
__device__ __forceinline__ void swizzle_tile(int L, int ncol, int& tile, int& col) {
    tile = (L / (8 * ncol)) * 8 + (L & 7);
    col  = (L >> 3) % ncol;
}

// ---------------- grouped gemm1: h[hb+s,:] = relu(X[tok_s,:] @ W1[e] + b1[e])
__global__ __launch_bounds__(256, 4)
void k_gemm1(const __hip_bfloat16* __restrict__ Xb,
             const __hip_bfloat16* __restrict__ W1bT,
             const float* __restrict__ b1,
             const int* __restrict__ count,
             const int* __restrict__ list,
             const int* __restrict__ hbase,
             const int* __restrict__ tileExpert,
             const int* __restrict__ tileRow,
             const int* __restrict__ nTiles,
             __hip_bfloat16* __restrict__ hbuf) {
    int tile, colT;
    swizzle_tile(blockIdx.x, HD / BN, tile, colT);
    if (tile >= *nTiles) return;
    const int e   = tileExpert[tile];
    const int m0  = tileRow[tile] * BM;
    const int cnt = count[e];
    const int hb  = hbase[e];
    const int n0  = colT * BN;

    __shared__ alignas(16) __hip_bfloat16 As[BM * BK];   // [m][k], stride 64
    __shared__ alignas(16) __hip_bfloat16 Bs[BN * BK];   // [n][k], stride 64
    const int t = threadIdx.x;
    const int colg = t & 7;
    const __hip_bfloat16* ag[4];
    const __hip_bfloat16* bg[4];
#pragma unroll
    for (int i = 0; i < 4; ++i) {
        int row = (i * 256 + t) >> 3;                    // 0..127
        int s = m0 + row; if (s >= cnt) s = cnt - 1;     // clamp tail (no OOB)
        int tok = list[e * N_TOK + s];
        ag[i] = Xb + (size_t)tok * DM + colg * 8;
        bg[i] = W1bT + (size_t)e * HD * DM + (size_t)(n0 + row) * DM + colg * 8;
    }
    const int lane = t & 63, wave = t >> 6;
    const int wm = (wave & 1) * 64, wn = (wave >> 1) * 64;
    const int lm = lane & 15, quad = lane >> 4;
    f32x4 acc[4][4];
#pragma unroll
    for (int a = 0; a < 4; ++a)
#pragma unroll
        for (int b = 0; b < 4; ++b) acc[a][b] = (f32x4){0.f, 0.f, 0.f, 0.f};

    for (int k0 = 0; k0 < DM; k0 += BK) {
#pragma unroll
        for (int i = 0; i < 4; ++i)
            async_copy16(ag[i] + k0, (char*)As + (i * 256 + t) * 16);
#pragma unroll
        for (int i = 0; i < 4; ++i)
            async_copy16(bg[i] + k0, (char*)Bs + (i * 256 + t) * 16);
        __syncthreads();
#pragma unroll
        for (int kk = 0; kk < BK; kk += 32) {
            bf16x8 av[4], bv[4];
#pragma unroll
            for (int mt = 0; mt < 4; ++mt)
                av[mt] = *(const bf16x8*)(As + (wm + mt * 16 + lm) * BK + kk + quad * 8);
#pragma unroll
            for (int nt = 0; nt < 4; ++nt)
                bv[nt] = *(const bf16x8*)(Bs + (wn + nt * 16 + lm) * BK + kk + quad * 8);
#pragma unroll
            for (int mt = 0; mt < 4; ++mt)
#pragma unroll
                for (int nt = 0; nt < 4; ++nt)
                    acc[mt][nt] = __builtin_amdgcn_mfma_f32_16x16x32_bf16(
                        av[mt], bv[nt], acc[mt][nt], 0, 0, 0);
        }
        __syncthreads();
    }
    // epilogue: bias + relu -> bf16 h at global slot hb+s
#pragma unroll
    for (int mt = 0; mt < 4; ++mt) {
#pragma unroll
        for (int r = 0; r < 4; ++r) {
            int s = m0 + wm + mt * 16 + quad * 4 + r;
            if (s < cnt) {
                __hip_bfloat16* hrow = hbuf + (size_t)(hb + s) * HD;
#pragma unroll
                for (int nt = 0; nt < 4; ++nt) {
                    int hc = n0 + wn + nt * 16 + lm;
                    float v = acc[mt][nt][r] + b1[e * HD + hc];
                    hrow[hc] = __float2bfloat16(fmaxf(v, 0.f));
                }
            }
        }
    }
}

// ---------------- grouped gemm2: out[tok,:] += gate*(h[hb+s,:] @ W2[e] + b2[e])
__global__ __launch_bounds__(256, 4)
void k_gemm2(const __hip_bfloat16* __restrict__ hbuf,
             const __hip_bfloat16* __restrict__ W2bT,
             const float* __restrict__ b2,
             const int* __restrict__ count,
             const int* __restrict__ list,
             const float* __restrict__ gatev,
             const int* __restrict__ hbase,
             const int* __restrict__ tileExpert,
             const int* __restrict__ tileRow,
             const int* __restrict__ nTiles,
             float* __restrict__ out) {
    int tile, colT;
    swizzle_tile(blockIdx.x, DM / BN, tile, colT);
    if (tile >= *nTiles) return;
    const int e   = tileExpert[tile];
    const int m0  = tileRow[tile] * BM;
    const int cnt = count[e];
    const int hb  = hbase[e];
    const int n0  = colT * BN;

    __shared__ alignas(16) __hip_bfloat16 As[BM * BK];
    __shared__ alignas(16) __hip_bfloat16 Bs[BN * BK];
    __shared__ int   stok[BM];
    __shared__ float sgate[BM];
    const int t = threadIdx.x;
    if (t < BM) {
        int s = m0 + t; if (s >= cnt) s = cnt - 1;
        stok[t]  = list[e * N_TOK + s];
        sgate[t] = gatev[e * N_TOK + s];
    }
    const int colg = t & 7;
    const __hip_bfloat16* ag[4];
    const __hip_bfloat16* bg[4];
#pragma unroll
    for (int i = 0; i < 4; ++i) {
        int row = (i * 256 + t) >> 3;
        int s = m0 + row; if (s >= cnt) s = cnt - 1;      // clamp: stay in this expert's h rows
        ag[i] = hbuf + (size_t)(hb + s) * HD + colg * 8;
        bg[i] = W2bT + (size_t)e * DM * HD + (size_t)(n0 + row) * HD + colg * 8;
    }
    const int lane = t & 63, wave = t >> 6;
    const int wm = (wave & 1) * 64, wn = (wave >> 1) * 64;
    const int lm = lane & 15, quad = lane >> 4;
    f32x4 acc[4][4];
#pragma unroll
    for (int a = 0; a < 4; ++a)
#pragma unroll
        for (int b = 0; b < 4; ++b) acc[a][b] = (f32x4){0.f, 0.f, 0.f, 0.f};

    for (int k0 = 0; k0 < HD; k0 += BK) {
#pragma unroll
        for (int i = 0; i < 4; ++i)
            async_copy16(ag[i] + k0, (char*)As + (i * 256 + t) * 16);
#pragma unroll
        for (int i = 0; i < 4; ++i)
            async_copy16(bg[i] + k0, (char*)Bs + (i * 256 + t) * 16);
        __syncthreads();
#pragma unroll
        for (int kk = 0; kk < BK; kk += 32) {
            bf16x8 av[4], bv[4];
#pragma unroll
            for (int mt = 0; mt < 4; ++mt)
                av[mt] = *(const bf16x8*)(As + (wm + mt * 16 + lm) * BK + kk + quad * 8);
#pragma unroll
            for (int nt = 0; nt < 4; ++nt)
                bv[nt] = *(const bf16x8*)(Bs + (wn + nt * 16 + lm) * BK + kk + quad * 8);
#pragma unroll
            for (int mt = 0; mt < 4; ++mt)
#pragma unroll
                for (int nt = 0; nt < 4; ++nt)
                    acc[mt][nt] = __builtin_amdgcn_mfma_f32_16x16x32_bf16(
                        av[mt], bv[nt], acc[mt][nt], 0, 0, 0);
        }
        __syncthreads();
    }
    // epilogue: atomic accumulate gate*(acc + b2) into out
    // (each out element receives exactly TOPK=2 adds -> commutative -> deterministic)
#pragma unroll
    for (int mt = 0; mt < 4; ++mt) {
#pragma unroll
        for (int r = 0; r < 4; ++r) {
            int srow = wm + mt * 16 + quad * 4 + r;
            int s = m0 + srow;
            if (s < cnt) {
                int tok = stok[srow];
                float g = sgate[srow];
                float* orow = out + (size_t)tok * DM;
#pragma unroll
                for (int nt = 0; nt < 4; ++nt) {
                    int dc = n0 + wn + nt * 16 + lm;
                    unsafeAtomicAdd(&orow[dc], g * (acc[mt][nt][r] + b2[e * DM + dc]));
                }
            }
        }
    }
}

// ---------------- launch ----------------------------------------------------
extern "C" void kernel_launch(void* const* d_in, const int* in_sizes, int n_in,
                              void* d_out, int out_size, void* d_ws, size_t ws_size,
                              hipStream_t stream) {
    const float* X  = (const float*)d_in[0];
    const float* Wr = (const float*)d_in[1];
    const float* W1 = (const float*)d_in[2];
    const float* b1 = (const float*)d_in[3];
    const float* W2 = (const float*)d_in[4];
    const float* b2 = (const float*)d_in[5];
    float* out = (float*)d_out;

    // workspace layout (bytes)
    char* ws = (char*)d_ws;
    __hip_bfloat16* Xb   = (__hip_bfloat16*)(ws + 0);          // N*D*2        = 16,777,216
    __hip_bfloat16* W1bT = (__hip_bfloat16*)(ws + 16777216);   // E*H*D*2      = 16,777,216
    __hip_bfloat16* W2bT = (__hip_bfloat16*)(ws + 33554432);   // E*D*H*2      = 16,777,216
    __hip_bfloat16* hbuf = (__hip_bfloat16*)(ws + 50331648);   // N*K*H*2      = 134,217,728
    int*   list  = (int*)  (ws + 184549376);                   // E*N*4        = 524,288
    float* gatev = (float*)(ws + 185073664);                   // E*N*4        = 524,288
    int*   count = (int*)  (ws + 185597952);                   // 32
    int*   hbase = (int*)  (ws + 185598016);                   // 32
    int*   tileE = (int*)  (ws + 185598080);                   // 1056
    int*   tileR = (int*)  (ws + 185599168);                   // 1056
    int*   nTil  = (int*)  (ws + 185600256);                   // 4

    k_init<<<dim3(8192), 256, 0, stream>>>(out, count);
    k_transpose<<<dim3(HD / 32, DM / 32, NE), 256, 0, stream>>>(W1, W1bT, DM, HD);
    k_transpose<<<dim3(DM / 32, HD / 32, NE), 256, 0, stream>>>(W2, W2bT, HD, DM);
    k_router<<<dim3(N_TOK / RT_TOK), RT_TOK, 0, stream>>>(X, Wr, count, list, gatev, (uint2*)Xb);
    k_sched<<<dim3(1), 64, 0, stream>>>(count, hbase, tileE, tileR, nTil);
    // 1D swizzled grids: gemm1 = 264*16 = 4224 blocks, gemm2 = 264*4 = 1056
    k_gemm1<<<dim3(MAX_TILES * (HD / BN)), 256, 0, stream>>>(Xb, W1bT, b1, count, list,
                                                             hbase, tileE, tileR, nTil, hbuf);
    k_gemm2<<<dim3(MAX_TILES * (DM / BN)), 256, 0, stream>>>(hbuf, W2bT, b2, count, list, gatev,
                                                             hbase, tileE, tileR, nTil, out);
}

// Round 4
// 416.995 us; speedup vs baseline: 1.3095x; 1.3095x over previous
//
#include <hip/hip_runtime.h>
#include <hip/hip_bf16.h>
#include <cstdint>
#include <cstddef>

// MoE dims (fixed by the problem)
#define N_TOK 16384
#define DM    512
#define HD    2048
#define NE    8
#define TOPK  2

// GEMM tiling
#define BM 128
#define BN 128
#define BK 64
#define MAX_TILES 264   // sum ceil(count_e/128), sum count = 32768 -> <= 256+8

// Router tiling
#define RT_TOK 128
#define RT_DC  32

typedef __bf16  bf16x8 __attribute__((ext_vector_type(8)));
typedef float   f32x4  __attribute__((ext_vector_type(4)));

typedef const __attribute__((address_space(1))) void* gas_ptr;
typedef __attribute__((address_space(3))) void*       las_ptr;

__device__ __forceinline__ void async_copy16(const void* g, void* l) {
    __builtin_amdgcn_global_load_lds((gas_ptr)g, (las_ptr)l, 16, 0, 0);
}

// ---------------- init: zero expert counts ----------------------------------
__global__ void k_init(int* __restrict__ count) {
    if (threadIdx.x < NE) count[threadIdx.x] = 0;
}

// ---------------- per-expert transpose + convert: [E][R][C] f32 -> [E][C][R] bf16
__global__ void k_transpose(const float* __restrict__ in, __hip_bfloat16* __restrict__ outp,
                            int R, int C) {
    __shared__ float tile[32][33];
    const int e = blockIdx.z;
    const float* A = in + (size_t)e * R * C;
    __hip_bfloat16* B = outp + (size_t)e * R * C;
    const int c0 = blockIdx.x * 32, r0 = blockIdx.y * 32;
    const int tx = threadIdx.x & 31, ty = threadIdx.x >> 5;   // 32 x 8
#pragma unroll
    for (int i = 0; i < 32; i += 8)
        tile[ty + i][tx] = A[(size_t)(r0 + ty + i) * C + c0 + tx];
    __syncthreads();
#pragma unroll
    for (int i = 0; i < 32; i += 8)
        B[(size_t)(c0 + ty + i) * R + r0 + tx] = __float2bfloat16(tile[tx][ty + i]);
}

// ---------------- router: thread-per-token, LDS-staged X; fuses X->bf16 -----
__global__ __launch_bounds__(RT_TOK)
void k_router(const float* __restrict__ X, const float* __restrict__ Wr,
              int* __restrict__ count, int* __restrict__ list,
              int* __restrict__ tokexp, int* __restrict__ tokpos,
              float* __restrict__ tokgate, uint2* __restrict__ Xb4) {
    __shared__ float sW[DM * NE];              // 16 KB, [d][e] row-major like Wr
    __shared__ float sX[RT_TOK][RT_DC + 1];    // +1 pad: lanes hit 2/bank (free)
    const int t = threadIdx.x;
    const int tok = blockIdx.x * RT_TOK + t;
    for (int i = t; i < DM * NE; i += RT_TOK) sW[i] = Wr[i];

    double acc[NE];
#pragma unroll
    for (int e = 0; e < NE; ++e) acc[e] = 0.0;

    const float4* X4 = (const float4*)X;
    for (int d0 = 0; d0 < DM; d0 += RT_DC) {
        __syncthreads();
        const int base4 = blockIdx.x * RT_TOK * (DM / 4) + d0 / 4;
#pragma unroll
        for (int j = 0; j < (RT_TOK * RT_DC / 4) / RT_TOK; ++j) {  // 8 float4/thread
            int i = t + RT_TOK * j;
            int r = i >> 3, c4 = i & 7;                   // RT_DC/4 = 8 vec4 per row
            float4 v = X4[base4 + r * (DM / 4) + c4];
            sX[r][c4 * 4 + 0] = v.x;
            sX[r][c4 * 4 + 1] = v.y;
            sX[r][c4 * 4 + 2] = v.z;
            sX[r][c4 * 4 + 3] = v.w;
            // fused fp32 -> bf16 convert
            union { __hip_bfloat16 h[4]; uint2 u; } cv;
            cv.h[0] = __float2bfloat16(v.x);
            cv.h[1] = __float2bfloat16(v.y);
            cv.h[2] = __float2bfloat16(v.z);
            cv.h[3] = __float2bfloat16(v.w);
            Xb4[base4 + r * (DM / 4) + c4] = cv.u;
        }
        __syncthreads();
#pragma unroll
        for (int j = 0; j < RT_DC; ++j) {
            double xv = (double)sX[t][j];
            const float* w = &sW[(d0 + j) * NE];
#pragma unroll
            for (int e = 0; e < NE; ++e) acc[e] += xv * (double)w[e];
        }
    }

    // softmax + top-2 (ties -> lowest index, matching jax.lax.top_k)
    double mx = acc[0];
#pragma unroll
    for (int e = 1; e < NE; ++e) mx = acc[e] > mx ? acc[e] : mx;
    double p[NE], sum = 0.0;
#pragma unroll
    for (int e = 0; e < NE; ++e) { p[e] = exp(acc[e] - mx); sum += p[e]; }
    int i1 = 0;
#pragma unroll
    for (int e = 1; e < NE; ++e) if (acc[e] > acc[i1]) i1 = e;
    int i2 = (i1 == 0) ? 1 : 0;
#pragma unroll
    for (int e = 0; e < NE; ++e) {
        if (e == i1 || e == i2) continue;
        if (acc[e] > acc[i2]) i2 = e;
    }
    float v1 = (float)(p[i1] / sum), v2 = (float)(p[i2] / sum);

    // wave-aggregated append: <=16 atomics per wave instead of 128
    const int lane = t & 63;
#pragma unroll
    for (int k = 0; k < TOPK; ++k) {
        int   my_e = (k == 0) ? i1 : i2;
        float my_v = (k == 0) ? v1 : v2;
        for (int e = 0; e < NE; ++e) {
            unsigned long long msk = __ballot(my_e == e);
            if (!msk) continue;
            int leader = __ffsll(msk) - 1;
            int base = 0;
            if (lane == leader) base = atomicAdd(&count[e], __popcll(msk));
            base = __shfl(base, leader);
            if (my_e == e) {
                int pos = base + __popcll(msk & ((1ull << lane) - 1));
                list[e * N_TOK + pos]   = tok;
                tokexp[2 * tok + k]     = e;
                tokpos[2 * tok + k]     = pos;
                tokgate[2 * tok + k]    = my_v;
            }
        }
    }
}

// ---------------- schedule: per-expert tile list + h-row prefix bases -------
__global__ void k_sched(const int* __restrict__ count, int* __restrict__ hbase,
                        int* __restrict__ tileExpert, int* __restrict__ tileRow,
                        int* __restrict__ nTiles) {
    if (threadIdx.x == 0 && blockIdx.x == 0) {
        int hb = 0, tc = 0;
        for (int e = 0; e < NE; ++e) {
            hbase[e] = hb;
            int tiles = (count[e] + BM - 1) / BM;
            for (int i = 0; i < tiles; ++i) { tileExpert[tc] = e; tileRow[tc] = i; ++tc; }
            hb += count[e];
        }
        *nTiles = tc;
    }
}

// XCD-aware swizzle: the NCOL column-tiles of one row-tile get block ids that
// are congruent mod 8 -> same XCD -> the A row-slab is fetched once per XCD.
__device__ __forceinline__ void swizzle_tile(int L, int ncol, int& tile, int& col) {
    tile = (L / (8 * ncol)) * 8 + (L & 7);
    col  = (L >> 3) % ncol;
}

// ---------------- grouped gemm1: h[hb+s,:] = relu(X[tok_s,:] @ W1[e] + b1[e])
// LDS layout XOR-swizzled: row r's global 16B-granule g lives at slot g^(r&7).
__global__ __launch_bounds__(256, 3)
void k_gemm1(const __hip_bfloat16* __restrict__ Xb,
             const __hip_bfloat16* __restrict__ W1bT,
             const float* __restrict__ b1,
             const int* __restrict__ count,
             const int* __restrict__ list,
             const int* __restrict__ hbase,
             const int* __restrict__ tileExpert,
             const int* __restrict__ tileRow,
             const int* __restrict__ nTiles,
             __hip_bfloat16* __restrict__ hbuf) {
    int tile, colT;
    swizzle_tile(blockIdx.x, HD / BN, tile, colT);
    if (tile >= *nTiles) return;
    const int e   = tileExpert[tile];
    const int m0  = tileRow[tile] * BM;
    const int cnt = count[e];
    const int hb  = hbase[e];
    const int n0  = colT * BN;

    __shared__ alignas(16) __hip_bfloat16 As[BM * BK];   // [m][slot], stride 64
    __shared__ alignas(16) __hip_bfloat16 Bs[BN * BK];
    const int t = threadIdx.x;
    const int colg = t & 7;
    const __hip_bfloat16* ag[4];
    const __hip_bfloat16* bg[4];
#pragma unroll
    for (int i = 0; i < 4; ++i) {
        int row = (i * 256 + t) >> 3;                    // 0..127 tile-local
        int gsrc = colg ^ (row & 7);                     // XOR source permutation
        int s = m0 + row; if (s >= cnt) s = cnt - 1;     // clamp tail (no OOB)
        int tok = list[e * N_TOK + s];
        ag[i] = Xb + (size_t)tok * DM + gsrc * 8;
        bg[i] = W1bT + (size_t)e * HD * DM + (size_t)(n0 + row) * DM + gsrc * 8;
    }
    const int lane = t & 63, wave = t >> 6;
    const int wm = (wave & 1) * 64, wn = (wave >> 1) * 64;
    const int lm = lane & 15, quad = lane >> 4;
    f32x4 acc[4][4];
#pragma unroll
    for (int a = 0; a < 4; ++a)
#pragma unroll
        for (int b = 0; b < 4; ++b) acc[a][b] = (f32x4){0.f, 0.f, 0.f, 0.f};

    for (int k0 = 0; k0 < DM; k0 += BK) {
#pragma unroll
        for (int i = 0; i < 4; ++i)
            async_copy16(ag[i] + k0, (char*)As + (i * 256 + t) * 16);
#pragma unroll
        for (int i = 0; i < 4; ++i)
            async_copy16(bg[i] + k0, (char*)Bs + (i * 256 + t) * 16);
        __syncthreads();
#pragma unroll
        for (int kk = 0; kk < BK; kk += 32) {
            bf16x8 av[4], bv[4];
#pragma unroll
            for (int mt = 0; mt < 4; ++mt) {
                int r = wm + mt * 16 + lm, g = (kk >> 3) + quad;
                av[mt] = *(const bf16x8*)(As + r * BK + ((g ^ (r & 7)) << 3));
            }
#pragma unroll
            for (int nt = 0; nt < 4; ++nt) {
                int r = wn + nt * 16 + lm, g = (kk >> 3) + quad;
                bv[nt] = *(const bf16x8*)(Bs + r * BK + ((g ^ (r & 7)) << 3));
            }
#pragma unroll
            for (int mt = 0; mt < 4; ++mt)
#pragma unroll
                for (int nt = 0; nt < 4; ++nt)
                    acc[mt][nt] = __builtin_amdgcn_mfma_f32_16x16x32_bf16(
                        av[mt], bv[nt], acc[mt][nt], 0, 0, 0);
        }
        __syncthreads();
    }
    // epilogue: bias + relu -> bf16 h at global slot hb+s
#pragma unroll
    for (int mt = 0; mt < 4; ++mt) {
#pragma unroll
        for (int r = 0; r < 4; ++r) {
            int s = m0 + wm + mt * 16 + quad * 4 + r;
            if (s < cnt) {
                __hip_bfloat16* hrow = hbuf + (size_t)(hb + s) * HD;
#pragma unroll
                for (int nt = 0; nt < 4; ++nt) {
                    int hc = n0 + wn + nt * 16 + lm;
                    float v = acc[mt][nt][r] + b1[e * HD + hc];
                    hrow[hc] = __float2bfloat16(fmaxf(v, 0.f));
                }
            }
        }
    }
}

// ---------------- grouped gemm2: y[hb+s,:] = h[hb+s,:] @ W2[e] + b2[e] ------
// No gather, no atomics: slot-contiguous bf16 stores; combine pass applies gates.
__global__ __launch_bounds__(256, 3)
void k_gemm2(const __hip_bfloat16* __restrict__ hbuf,
             const __hip_bfloat16* __restrict__ W2bT,
             const float* __restrict__ b2,
             const int* __restrict__ count,
             const int* __restrict__ hbase,
             const int* __restrict__ tileExpert,
             const int* __restrict__ tileRow,
             const int* __restrict__ nTiles,
             __hip_bfloat16* __restrict__ yb) {
    int tile, colT;
    swizzle_tile(blockIdx.x, DM / BN, tile, colT);
    if (tile >= *nTiles) return;
    const int e   = tileExpert[tile];
    const int m0  = tileRow[tile] * BM;
    const int cnt = count[e];
    const int hb  = hbase[e];
    const int n0  = colT * BN;

    __shared__ alignas(16) __hip_bfloat16 As[BM * BK];
    __shared__ alignas(16) __hip_bfloat16 Bs[BN * BK];
    const int t = threadIdx.x;
    const int colg = t & 7;
    const __hip_bfloat16* ag[4];
    const __hip_bfloat16* bg[4];
#pragma unroll
    for (int i = 0; i < 4; ++i) {
        int row = (i * 256 + t) >> 3;
        int gsrc = colg ^ (row & 7);
        int s = m0 + row; if (s >= cnt) s = cnt - 1;
        ag[i] = hbuf + (size_t)(hb + s) * HD + gsrc * 8;
        bg[i] = W2bT + (size_t)e * DM * HD + (size_t)(n0 + row) * HD + gsrc * 8;
    }
    const int lane = t & 63, wave = t >> 6;
    const int wm = (wave & 1) * 64, wn = (wave >> 1) * 64;
    const int lm = lane & 15, quad = lane >> 4;
    f32x4 acc[4][4];
#pragma unroll
    for (int a = 0; a < 4; ++a)
#pragma unroll
        for (int b = 0; b < 4; ++b) acc[a][b] = (f32x4){0.f, 0.f, 0.f, 0.f};

    for (int k0 = 0; k0 < HD; k0 += BK) {
#pragma unroll
        for (int i = 0; i < 4; ++i)
            async_copy16(ag[i] + k0, (char*)As + (i * 256 + t) * 16);
#pragma unroll
        for (int i = 0; i < 4; ++i)
            async_copy16(bg[i] + k0, (char*)Bs + (i * 256 + t) * 16);
        __syncthreads();
#pragma unroll
        for (int kk = 0; kk < BK; kk += 32) {
            bf16x8 av[4], bv[4];
#pragma unroll
            for (int mt = 0; mt < 4; ++mt) {
                int r = wm + mt * 16 + lm, g = (kk >> 3) + quad;
                av[mt] = *(const bf16x8*)(As + r * BK + ((g ^ (r & 7)) << 3));
            }
#pragma unroll
            for (int nt = 0; nt < 4; ++nt) {
                int r = wn + nt * 16 + lm, g = (kk >> 3) + quad;
                bv[nt] = *(const bf16x8*)(Bs + r * BK + ((g ^ (r & 7)) << 3));
            }
#pragma unroll
            for (int mt = 0; mt < 4; ++mt)
#pragma unroll
                for (int nt = 0; nt < 4; ++nt)
                    acc[mt][nt] = __builtin_amdgcn_mfma_f32_16x16x32_bf16(
                        av[mt], bv[nt], acc[mt][nt], 0, 0, 0);
        }
        __syncthreads();
    }
    // epilogue: y = acc + b2 (bias folded here), bf16 streaming store
#pragma unroll
    for (int mt = 0; mt < 4; ++mt) {
#pragma unroll
        for (int r = 0; r < 4; ++r) {
            int s = m0 + wm + mt * 16 + quad * 4 + r;
            if (s < cnt) {
                __hip_bfloat16* yrow = yb + (size_t)(hb + s) * DM;
#pragma unroll
                for (int nt = 0; nt < 4; ++nt) {
                    int dc = n0 + wn + nt * 16 + lm;
                    yrow[dc] = __float2bfloat16(acc[mt][nt][r] + b2[e * DM + dc]);
                }
            }
        }
    }
}

// ---------------- combine: out[n,:] = g1*y[slot1,:] + g2*y[slot2,:] ---------
__global__ __launch_bounds__(256)
void k_combine(const __hip_bfloat16* __restrict__ yb,
               const int* __restrict__ hbase,
               const int* __restrict__ tokexp,
               const int* __restrict__ tokpos,
               const float* __restrict__ tokgate,
               float* __restrict__ out) {
    const int n = blockIdx.x * 4 + (threadIdx.x >> 6);   // wave per token
    const int lane = threadIdx.x & 63;
    const int s1 = hbase[tokexp[2 * n]]     + tokpos[2 * n];
    const int s2 = hbase[tokexp[2 * n + 1]] + tokpos[2 * n + 1];
    const float g1 = tokgate[2 * n], g2 = tokgate[2 * n + 1];
    uint4 a = ((const uint4*)(yb + (size_t)s1 * DM))[lane];   // 8 bf16
    uint4 b = ((const uint4*)(yb + (size_t)s2 * DM))[lane];
    float o[8];
    const unsigned* au = (const unsigned*)&a;
    const unsigned* bu = (const unsigned*)&b;
#pragma unroll
    for (int j = 0; j < 4; ++j) {
        union { unsigned u; float f; } alo, ahi, blo, bhi;
        alo.u = au[j] << 16; ahi.u = au[j] & 0xFFFF0000u;
        blo.u = bu[j] << 16; bhi.u = bu[j] & 0xFFFF0000u;
        o[2 * j]     = g1 * alo.f + g2 * blo.f;
        o[2 * j + 1] = g1 * ahi.f + g2 * bhi.f;
    }
    float4* orow = (float4*)(out + (size_t)n * DM);
    orow[lane * 2]     = make_float4(o[0], o[1], o[2], o[3]);
    orow[lane * 2 + 1] = make_float4(o[4], o[5], o[6], o[7]);
    if (blockIdx.x == 0 && threadIdx.x == 0) out[(size_t)N_TOK * DM] = 0.f;  // loss
}

// ---------------- launch ----------------------------------------------------
extern "C" void kernel_launch(void* const* d_in, const int* in_sizes, int n_in,
                              void* d_out, int out_size, void* d_ws, size_t ws_size,
                              hipStream_t stream) {
    const float* X  = (const float*)d_in[0];
    const float* Wr = (const float*)d_in[1];
    const float* W1 = (const float*)d_in[2];
    const float* b1 = (const float*)d_in[3];
    const float* W2 = (const float*)d_in[4];
    const float* b2 = (const float*)d_in[5];
    float* out = (float*)d_out;

    // workspace layout (bytes). yb aliases Xb+W1bT: both dead once gemm1 completes
    // (stream-ordered before gemm2 writes yb).
    char* ws = (char*)d_ws;
    __hip_bfloat16* Xb   = (__hip_bfloat16*)(ws + 0);          // N*D*2        = 16,777,216
    __hip_bfloat16* W1bT = (__hip_bfloat16*)(ws + 16777216);   // E*H*D*2      = 16,777,216
    __hip_bfloat16* yb   = (__hip_bfloat16*)(ws + 0);          // 32K*D*2      = 33,554,432 (alias)
    __hip_bfloat16* W2bT = (__hip_bfloat16*)(ws + 33554432);   // E*D*H*2      = 16,777,216
    __hip_bfloat16* hbuf = (__hip_bfloat16*)(ws + 50331648);   // N*K*H*2      = 134,217,728
    int*   list   = (int*)  (ws + 184549376);                  // E*N*4        = 524,288
    int*   tokexp = (int*)  (ws + 185073664);                  // N*2*4        = 131,072
    int*   tokpos = (int*)  (ws + 185204736);                  // 131,072
    float* tokgate= (float*)(ws + 185335808);                  // 131,072
    int*   count  = (int*)  (ws + 185466880);                  // 32
    int*   hbase  = (int*)  (ws + 185466944);                  // 32
    int*   tileE  = (int*)  (ws + 185467008);                  // 1088
    int*   tileR  = (int*)  (ws + 185468096);                  // 1088
    int*   nTil   = (int*)  (ws + 185469184);                  // 4

    k_init<<<dim3(1), 64, 0, stream>>>(count);
    k_transpose<<<dim3(HD / 32, DM / 32, NE), 256, 0, stream>>>(W1, W1bT, DM, HD);
    k_transpose<<<dim3(DM / 32, HD / 32, NE), 256, 0, stream>>>(W2, W2bT, HD, DM);
    k_router<<<dim3(N_TOK / RT_TOK), RT_TOK, 0, stream>>>(X, Wr, count, list,
                                                          tokexp, tokpos, tokgate, (uint2*)Xb);
    k_sched<<<dim3(1), 64, 0, stream>>>(count, hbase, tileE, tileR, nTil);
    k_gemm1<<<dim3(MAX_TILES * (HD / BN)), 256, 0, stream>>>(Xb, W1bT, b1, count, list,
                                                             hbase, tileE, tileR, nTil, hbuf);
    k_gemm2<<<dim3(MAX_TILES * (DM / BN)), 256, 0, stream>>>(hbuf, W2bT, b2, count,
                                                             hbase, tileE, tileR, nTil, yb);
    k_combine<<<dim3(N_TOK / 4), 256, 0, stream>>>(yb, hbase, tokexp, tokpos, tokgate, out);
}